// Round 14
// baseline (24.344 us; speedup 1.0000x reference)
//
#include <hip/hip_runtime.h>

// Path signature depth 4, path (N=64, L=512, C=8) fp32. SINGLE kernel.
//
// One block per batch element: 64 blocks x 512 threads (8 waves). Wave w
// computes the 64-step chunk signature for increments [w*64, w*64+64) fully
// in registers (packed f2 math). Then an in-block depth-3 tree combine:
//   L1: (S0xS1)(S2xS3)(S4xS5)(S6xS7)  [4 products, 128 thr each]
//   L2: (P0xP1)(P2xP3)                [2 products, 256 thr each]
//   L3: Q0xQ1 -> out                  [512 thr]
// No workspace, no fences, no second dispatch (R6: fences catastrophic;
// R13: extra dispatches/blocks only add overhead; R12 floor was ~18.3us with
// 2 dispatches — this tests the dispatch-overhead hypothesis).
//
// LDS (158.4KB): sT[8][1024] f4 (L4, T-layout; sT[0] aliases the increment
// buffer zbuf — dead before publish), sL[8][648] (chunk L123; sL[0..1]
// reused as level-2 outputs Q0/Q1 after level 1), sP[4][648] (level-1 L123).
//
// L123 layouts: A-side (scalar): L1 [0,8), L2 [8,72), L3 at 72+(p*8+q)*9+r.
//               B-side (float4): L1/L2 flat, L3 at 72+x*72+y*8+z.
// L4 T-layout: f4 #i of lane l at i*64+l covers (a=l>>3,b=l&7,c=i>>1,
// d=(i&1)*4..+3).  R7 rule: every stored element is computed by its storer.

typedef float f2 __attribute__((ext_vector_type(2)));

#define NB 64
#define LP 512
#define SIG 4680
#define O2 8
#define O3 72
#define O4 584
#define SB 648

#define A3IDX(pq, r) (72 + (pq) * 9 + (r))
#define B3IDX(x, y, z) (72 + (x) * 72 + (y) * 8 + (z))

__device__ __forceinline__ f2 mkf2(float x, float y) { f2 r; r[0] = x; r[1] = y; return r; }

__global__ __launch_bounds__(512) void k_all(const float* __restrict__ path,
                                             float* __restrict__ out)
{
    __shared__ __align__(16) float4 sT[8][1024];   // 128 KB
    __shared__ __align__(16) float sL[8][SB];      // 20.25 KB
    __shared__ __align__(16) float sP[4][SB];      // 10.125 KB
    float* const zbuf = (float*)&sT[0][0];         // 16 KB alias (dead at publish)

    const int tid = threadIdx.x;
    const int n = blockIdx.x;

    // ---- stage all 511 increments (row tid; zero row 511) ----
    {
        const float4* p4 = (const float4*)path + (size_t)n * (LP * 2);
        float4 zlo = make_float4(0.f, 0.f, 0.f, 0.f);
        float4 zhi = zlo;
        if (tid < LP - 1) {
            float4 a0 = p4[2 * tid],     a1 = p4[2 * tid + 1];
            float4 b0 = p4[2 * tid + 2], b1 = p4[2 * tid + 3];
            zlo = make_float4(b0.x - a0.x, b0.y - a0.y, b0.z - a0.z, b0.w - a0.w);
            zhi = make_float4(b1.x - a1.x, b1.y - a1.y, b1.z - a1.z, b1.w - a1.w);
        }
        ((float4*)zbuf)[2 * tid]     = zlo;
        ((float4*)zbuf)[2 * tid + 1] = zhi;
    }
    __syncthreads();

    const int w = tid >> 6, l = tid & 63;
    const int a = l >> 3, b = l & 7;

    // ---- 64-step chunk signature in registers (packed f2 math) ----
    float s1 = 0.f, s2 = 0.f;
    f2 s3p[4], s4p[32];
    #pragma unroll
    for (int i = 0; i < 4; ++i) s3p[i] = mkf2(0.f, 0.f);
    #pragma unroll
    for (int e = 0; e < 32; ++e) s4p[e] = mkf2(0.f, 0.f);

    const float* zw = zbuf + w * (64 * 8);
    #pragma unroll 4
    for (int s = 0; s < 64; ++s) {
        const float* zs = zw + s * 8;
        f2 zp[4];
        #pragma unroll
        for (int j = 0; j < 4; ++j) zp[j] = ((const f2*)zs)[j];
        const float za  = zs[a];
        const float zbv = zs[b];
        const float B4 = zbv * (za * (1.f/24.f) + s1 * (1.f/6.f)) + s2 * 0.5f;
        const float G3 = zbv * (za * (1.f/6.f)  + s1 * 0.5f)      + s2;
        f2 Acp[4];
        #pragma unroll
        for (int i = 0; i < 4; ++i) Acp[i] = B4 * zp[i] + s3p[i];
        #pragma unroll
        for (int c = 0; c < 8; ++c) {
            const float Ac = Acp[c >> 1][c & 1];
            #pragma unroll
            for (int j = 0; j < 4; ++j) s4p[c * 4 + j] += Ac * zp[j];
        }
        #pragma unroll
        for (int i = 0; i < 4; ++i) s3p[i] += G3 * zp[i];
        s2 += zbv * (za * 0.5f + s1);
        s1 += za;
    }
    __syncthreads();   // all zbuf reads done before sT[0] publish overwrites it

    // ---- publish: even w -> sL[w] A-layout, odd w -> B-layout; L4 -> sT[w]
    if ((w & 1) == 0) {
        float* SA = sL[w];
        if (b == 0) SA[a] = s1;
        SA[O2 + l] = s2;
        #pragma unroll
        for (int c = 0; c < 8; ++c) SA[A3IDX(l, c)] = s3p[c >> 1][c & 1];
    } else {
        float* SL = sL[w];
        if (b == 0) SL[a] = s1;
        SL[O2 + l] = s2;
        *(float4*)&SL[B3IDX(a, b, 0)] = make_float4(s3p[0][0], s3p[0][1], s3p[1][0], s3p[1][1]);
        *(float4*)&SL[B3IDX(a, b, 4)] = make_float4(s3p[2][0], s3p[2][1], s3p[3][0], s3p[3][1]);
    }
    #pragma unroll
    for (int i = 0; i < 16; ++i)
        sT[w][i * 64 + l] = make_float4(s4p[2*i][0], s4p[2*i][1], s4p[2*i+1][0], s4p[2*i+1][1]);
    __syncthreads();

    // ---- level 1: product q = tid>>7 combines S(2q) x S(2q+1), 128 thr ----
    {
        const int q  = tid >> 7;
        const int ht = tid & 127;
        const int hi = ht >> 6;
        const int la = (ht >> 3) & 7, lb = ht & 7;
        const float* SA  = sL[2 * q];         // A-layout
        const float* SBb = sL[2 * q + 1];     // B-layout
        float4* TA = sT[2 * q];               // in-place: becomes P(q).L4
        const float4* TB = sT[2 * q + 1];
        const int dh = hi * 4;
        const float A1  = SA[la];
        const float A2v = SA[O2 + la * 8 + lb];
        f2 b1p[2];
        *(float4*)&b1p[0] = *(const float4*)(SBb + dh);
        #pragma unroll
        for (int k = 0; k < 8; ++k) {         // k = c index
            const int f = k * 128 + ht;
            const float A3c = SA[A3IDX(la * 8 + lb, k)];
            f2 b2p[2], b3p[2];
            *(float4*)&b2p[0] = *(const float4*)(SBb + O2 + k * 8 + dh);
            *(float4*)&b3p[0] = *(const float4*)(SBb + B3IDX(lb, k, dh));
            float4 av = TA[f], bv = TB[f];
            f2 r0 = mkf2(av.x, av.y) + mkf2(bv.x, bv.y)
                  + A3c * b1p[0] + A2v * b2p[0] + A1 * b3p[0];
            f2 r1 = mkf2(av.z, av.w) + mkf2(bv.z, bv.w)
                  + A3c * b1p[1] + A2v * b2p[1] + A1 * b3p[1];
            TA[f] = make_float4(r0[0], r0[1], r1[0], r1[1]);
        }
        // L123 product -> sP[q] (A-layout for even q, B-layout for odd q)
        float* OP = sP[q];
        const int f3 = ht * 4;
        const int pp = f3 >> 6, qq = (f3 >> 3) & 7, rr = f3 & 7;   // rr in {0,4}
        const float A1p  = SA[pp];
        const float A2pq = SA[O2 + pp * 8 + qq];
        f2 bb1[2], bb2[2], bb3[2];
        *(float4*)&bb1[0] = *(const float4*)(SBb + rr);
        *(float4*)&bb2[0] = *(const float4*)(SBb + O2 + qq * 8 + rr);
        *(float4*)&bb3[0] = *(const float4*)(SBb + B3IDX(pp, qq, rr));
        float o[4];
        #pragma unroll
        for (int j = 0; j < 4; ++j)
            o[j] = SA[A3IDX(pp * 8 + qq, rr + j)] + bb3[j >> 1][j & 1]
                 + A2pq * bb1[j >> 1][j & 1] + A1p * bb2[j >> 1][j & 1];
        if ((q & 1) == 0) {
            #pragma unroll
            for (int j = 0; j < 4; ++j) OP[A3IDX(pp * 8 + qq, rr + j)] = o[j];
        } else {
            *(float4*)&OP[B3IDX(pp, qq, rr)] = make_float4(o[0], o[1], o[2], o[3]);
        }
        if (ht < 64) OP[O2 + ht] = SA[O2 + ht] + SBb[O2 + ht] + SA[ht >> 3] * SBb[ht & 7];
        if (ht < 8)  OP[ht] = SA[ht] + SBb[ht];
    }
    __syncthreads();   // sL dead below (Q0/Q1 reuse sL[0..1])

    // ---- level 2: product h = tid>>8 combines P(2h) x P(2h+1), 256 thr ----
    {
        const int h  = tid >> 8;
        const int st = tid & 255;
        const int l2 = st & 63;
        const int la = l2 >> 3, lb = l2 & 7;
        const int hi2 = st >> 6;              // 0..3
        const int dh = (hi2 & 1) * 4;
        const float* PA = sP[2 * h];          // A-layout
        const float* PB = sP[2 * h + 1];      // B-layout
        float4* TA = sT[4 * h];               // in-place: Q(h).L4
        const float4* TB = sT[4 * h + 2];
        const float A1  = PA[la];
        const float A2v = PA[O2 + la * 8 + lb];
        f2 b1p[2];
        *(float4*)&b1p[0] = *(const float4*)(PB + dh);
        #pragma unroll
        for (int k = 0; k < 4; ++k) {
            const int f = k * 256 + st;
            const int c = 2 * k + (hi2 >> 1);
            const float A3c = PA[A3IDX(la * 8 + lb, c)];
            f2 b2p[2], b3p[2];
            *(float4*)&b2p[0] = *(const float4*)(PB + O2 + c * 8 + dh);
            *(float4*)&b3p[0] = *(const float4*)(PB + B3IDX(lb, c, dh));
            float4 av = TA[f], bv = TB[f];
            f2 r0 = mkf2(av.x, av.y) + mkf2(bv.x, bv.y)
                  + A3c * b1p[0] + A2v * b2p[0] + A1 * b3p[0];
            f2 r1 = mkf2(av.z, av.w) + mkf2(bv.z, bv.w)
                  + A3c * b1p[1] + A2v * b2p[1] + A1 * b3p[1];
            TA[f] = make_float4(r0[0], r0[1], r1[0], r1[1]);
        }
        // L123 -> Q(h): Q0 = sL[0] (A-layout), Q1 = sL[1] (B-layout)
        float* OQ = sL[h];
        const int f3 = 2 * st;
        const int pp = f3 >> 6, qq = (f3 >> 3) & 7, rr = f3 & 7;   // rr even
        const float A1p  = PA[pp];
        const float A2pq = PA[O2 + pp * 8 + qq];
        float v0 = PA[A3IDX(pp * 8 + qq, rr)]     + PB[B3IDX(pp, qq, rr)]
                 + A2pq * PB[rr]     + A1p * PB[O2 + qq * 8 + rr];
        float v1 = PA[A3IDX(pp * 8 + qq, rr + 1)] + PB[B3IDX(pp, qq, rr + 1)]
                 + A2pq * PB[rr + 1] + A1p * PB[O2 + qq * 8 + rr + 1];
        if (h == 0) {
            OQ[A3IDX(pp * 8 + qq, rr)]     = v0;
            OQ[A3IDX(pp * 8 + qq, rr + 1)] = v1;
        } else {
            OQ[B3IDX(pp, qq, rr)]     = v0;
            OQ[B3IDX(pp, qq, rr + 1)] = v1;
        }
        if (st < 64) OQ[O2 + st] = PA[O2 + st] + PB[O2 + st] + PA[st >> 3] * PB[st & 7];
        if (st < 8)  OQ[st] = PA[st] + PB[st];
    }
    __syncthreads();

    // ---- level 3: final = Q0 x Q1 -> out ----
    float* dst = out + (size_t)n * SIG;
    {
        const float* QA = sL[0];   // A-layout
        const float* QB = sL[1];   // B-layout
        const int dh4 = w & 1;
        const int c0  = w >> 1;
        const int dh  = dh4 * 4;
        const float A1  = QA[a];
        const float A2v = QA[O2 + a * 8 + b];
        f2 b1p[2];
        *(float4*)&b1p[0] = *(const float4*)(QB + dh);
        #pragma unroll
        for (int k = 0; k < 2; ++k) {
            const int c = 4 * k + c0;
            const int f = k * 512 + tid;       // = (8k + w)*64 + l
            const float A3c = QA[A3IDX(a * 8 + b, c)];
            f2 b2p[2], b3p[2];
            *(float4*)&b2p[0] = *(const float4*)(QB + O2 + c * 8 + dh);
            *(float4*)&b3p[0] = *(const float4*)(QB + B3IDX(b, c, dh));
            float4 av = sT[0][f], bv = sT[4][f];
            f2 r0 = mkf2(av.x, av.y) + mkf2(bv.x, bv.y)
                  + A3c * b1p[0] + A2v * b2p[0] + A1 * b3p[0];
            f2 r1 = mkf2(av.z, av.w) + mkf2(bv.z, bv.w)
                  + A3c * b1p[1] + A2v * b2p[1] + A1 * b3p[1];
            ((float4*)(dst + O4))[((a * 8 + b) * 8 + c) * 2 + dh4] =
                make_float4(r0[0], r0[1], r1[0], r1[1]);
        }
        // L123 final (each element computed by its storer)
        if (tid < 256) {
            const int f0 = 2 * tid;
            const int pp = f0 >> 6, qq = (f0 >> 3) & 7, rr = f0 & 7;
            const float A1p  = QA[pp];
            const float A2pq = QA[O2 + pp * 8 + qq];
            dst[O3 + f0]     = QA[A3IDX(pp*8+qq, rr)]     + QB[B3IDX(pp, qq, rr)]
                             + A2pq * QB[rr]     + A1p * QB[O2 + qq * 8 + rr];
            dst[O3 + f0 + 1] = QA[A3IDX(pp*8+qq, rr + 1)] + QB[B3IDX(pp, qq, rr + 1)]
                             + A2pq * QB[rr + 1] + A1p * QB[O2 + qq * 8 + rr + 1];
        }
        if (tid < 64) dst[O2 + tid] = QA[O2 + tid] + QB[O2 + tid] + QA[tid >> 3] * QB[tid & 7];
        if (tid < 8)  dst[tid] = QA[tid] + QB[tid];
    }
}

extern "C" void kernel_launch(void* const* d_in, const int* in_sizes, int n_in,
                              void* d_out, int out_size, void* d_ws, size_t ws_size,
                              hipStream_t stream) {
    const float* path = (const float*)d_in[0];
    float* out = (float*)d_out;
    (void)d_ws; (void)ws_size;

    k_all<<<NB, 512, 0, stream>>>(path, out);
}

// Round 15
// 18.350 us; speedup vs baseline: 1.3267x; 1.3267x over previous
//
#include <hip/hip_runtime.h>

// Path signature depth 4, path (N=64, L=512, C=8) fp32. Two kernels.
// FINAL (R12 structure — measured best, 18.31us).
//
// k1: 256 blocks (n, g 0..3), 4 waves. Wave w: 32-step chunk signature fully
//     in registers (lane (a,b) owns S4[a][b][*][*] as f2 pairs ->
//     v_pk_fma_f32). Then a TREE combine: level 1 = (S0xS1) and (S2xS3)
//     concurrently (L4 in-place in LDS by 128-thread halves, L123 to fresh
//     buffers); level 2 = final product, every element computed by its
//     storing thread. 3 barriers, 2 serial products.
// k2: 256 blocks (n, c-quadrant w4): same 2-level tree on the 4 partials.
//     L123 redundantly computed per quadrant block; w4==0 stores it.
//
// Structure-space results (this session): 2-dispatch/32-step/shallow-tree is
// the optimum. 1-dispatch = 1/4 chip (24.3us); fence handoff ~107us (R6);
// 16-step chunks lose to combine overhead (21.6-23.9); serial chains scale
// at ~0.7us/product past depth 2 (R11). Floor = 2 launches (~7-9us) +
// issue-bound 32-step chunk chain + 2+2 serial products.
//
// LDS layouts for L123:
//   A-side (scalar access):  L1 [0,8), L2 [8,72), L3 at 72+(p*8+q)*9+r
//   B-side (float4 access):  L1/L2 flat,           L3 at 72+x*72+y*8+z
// L4 T-layout: float4 #i of lane l at f4-index i*64+l, covering
// (a=l>>3, b=l&7, c=i>>1, d=(i&1)*4..+3).

typedef float f2 __attribute__((ext_vector_type(2)));

#define NB 64
#define LP 512
#define SIG 4680
#define O2 8
#define O3 72
#define O4 584
#define SB 648

#define A3IDX(pq, r) (72 + (pq) * 9 + (r))
#define B3IDX(x, y, z) (72 + (x) * 72 + (y) * 8 + (z))

__device__ __forceinline__ f2 mkf2(float x, float y) { f2 r; r[0] = x; r[1] = y; return r; }

// ---------------------------------------------------------------------------
// k1: 256 blocks x 256 thr. 32-step chunks + in-block TREE combine.
// ---------------------------------------------------------------------------
__global__ __launch_bounds__(256) void k1_sig(const float* __restrict__ path,
                                              float* __restrict__ ws)
{
    __shared__ __align__(16) float zbuf[128 * 8];
    __shared__ __align__(16) float sA0[SB], sB1[SB], sA2[SB], sB3[SB];
    __shared__ __align__(16) float sPA[SB], sPB[SB];
    __shared__ __align__(16) float4 sT[4][1024];

    const int tid = threadIdx.x;
    const int n = blockIdx.x >> 2;
    const int g = blockIdx.x & 3;

    {   // stage 128 increments (zero-padded past t=510; exp(0) = identity)
        const int r = tid >> 1, hh = tid & 1;
        const int t = g * 128 + r;
        const float4* p4 = (const float4*)path + (size_t)n * (LP * 2);
        float4 z4 = make_float4(0.f, 0.f, 0.f, 0.f);
        if (t < LP - 1) {
            float4 x0 = p4[t * 2 + hh];
            float4 x1 = p4[t * 2 + 2 + hh];
            z4 = make_float4(x1.x - x0.x, x1.y - x0.y, x1.z - x0.z, x1.w - x0.w);
        }
        ((float4*)zbuf)[tid] = z4;
    }
    __syncthreads();

    const int w = tid >> 6, l = tid & 63;
    const int a = l >> 3, b = l & 7;
    const int f0 = 2 * tid;

    // ---- 32-step chunk signature in registers (packed f2 math) ----
    float s1 = 0.f, s2 = 0.f;
    f2 s3p[4], s4p[32];
    #pragma unroll
    for (int i = 0; i < 4; ++i) s3p[i] = mkf2(0.f, 0.f);
    #pragma unroll
    for (int e = 0; e < 32; ++e) s4p[e] = mkf2(0.f, 0.f);

    const float* zw = zbuf + w * (32 * 8);
    #pragma unroll 4
    for (int s = 0; s < 32; ++s) {
        const float* zs = zw + s * 8;
        f2 zp[4];
        #pragma unroll
        for (int j = 0; j < 4; ++j) zp[j] = ((const f2*)zs)[j];
        const float za  = zs[a];
        const float zbv = zs[b];
        const float B4 = zbv * (za * (1.f/24.f) + s1 * (1.f/6.f)) + s2 * 0.5f;
        const float G3 = zbv * (za * (1.f/6.f)  + s1 * 0.5f)      + s2;
        f2 Acp[4];
        #pragma unroll
        for (int i = 0; i < 4; ++i) Acp[i] = B4 * zp[i] + s3p[i];
        #pragma unroll
        for (int c = 0; c < 8; ++c) {
            const float Ac = Acp[c >> 1][c & 1];
            #pragma unroll
            for (int j = 0; j < 4; ++j) s4p[c * 4 + j] += Ac * zp[j];
        }
        #pragma unroll
        for (int i = 0; i < 4; ++i) s3p[i] += G3 * zp[i];
        s2 += zbv * (za * 0.5f + s1);
        s1 += za;
    }

    // ---- publish: S0->sA0, S2->sA2 (A-layout); S1->sB1, S3->sB3 (B-layout);
    //      all L4 -> sT[w] (T-layout) ----
    if ((w & 1) == 0) {
        float* SA = (w == 0) ? sA0 : sA2;
        if (b == 0) SA[a] = s1;
        SA[O2 + l] = s2;
        #pragma unroll
        for (int c = 0; c < 8; ++c) SA[A3IDX(l, c)] = s3p[c >> 1][c & 1];
    } else {
        float* SL = (w == 1) ? sB1 : sB3;
        if (b == 0) SL[a] = s1;
        SL[O2 + l] = s2;
        *(float4*)&SL[B3IDX(a, b, 0)] = make_float4(s3p[0][0], s3p[0][1], s3p[1][0], s3p[1][1]);
        *(float4*)&SL[B3IDX(a, b, 4)] = make_float4(s3p[2][0], s3p[2][1], s3p[3][0], s3p[3][1]);
    }
    #pragma unroll
    for (int i = 0; i < 16; ++i)
        sT[w][i * 64 + l] = make_float4(s4p[2*i][0], s4p[2*i][1], s4p[2*i+1][0], s4p[2*i+1][1]);
    __syncthreads();

    // ---- level 1: half 0 -> P01 = S0 x S1, half 1 -> P23 = S2 x S3 ----
    {
        const int h  = tid >> 7;
        const int ht = tid & 127;
        const int hi = ht >> 6;
        const int la = (ht >> 3) & 7, lb = ht & 7;
        const float* SA  = h ? sA2 : sA0;
        const float* SBb = h ? sB3 : sB1;
        float4* TA = sT[h ? 2 : 0];          // in-place: becomes P.L4
        const float4* TB = sT[h ? 3 : 1];
        const int dh = hi * 4;
        const float A1  = SA[la];
        const float A2v = SA[O2 + la * 8 + lb];
        f2 b1p[2];
        *(float4*)&b1p[0] = *(const float4*)(SBb + dh);
        #pragma unroll
        for (int k = 0; k < 8; ++k) {        // k = c index
            const int f = k * 128 + ht;
            const float A3c = SA[A3IDX(la * 8 + lb, k)];
            f2 b2p[2], b3p[2];
            *(float4*)&b2p[0] = *(const float4*)(SBb + O2 + k * 8 + dh);
            *(float4*)&b3p[0] = *(const float4*)(SBb + B3IDX(lb, k, dh));
            float4 av = TA[f], bv = TB[f];
            f2 r0 = mkf2(av.x, av.y) + mkf2(bv.x, bv.y)
                  + A3c * b1p[0] + A2v * b2p[0] + A1 * b3p[0];
            f2 r1 = mkf2(av.z, av.w) + mkf2(bv.z, bv.w)
                  + A3c * b1p[1] + A2v * b2p[1] + A1 * b3p[1];
            TA[f] = make_float4(r0[0], r0[1], r1[0], r1[1]);
        }
        // L123 of the half's product: P01 -> sPA (A-layout), P23 -> sPB (B-layout)
        float* OP = h ? sPB : sPA;
        const int f3 = ht * 4;
        const int pp = f3 >> 6, qq = (f3 >> 3) & 7, rr = f3 & 7;   // rr in {0,4}
        const float A1p  = SA[pp];
        const float A2pq = SA[O2 + pp * 8 + qq];
        f2 bb1[2], bb2[2], bb3[2];
        *(float4*)&bb1[0] = *(const float4*)(SBb + rr);
        *(float4*)&bb2[0] = *(const float4*)(SBb + O2 + qq * 8 + rr);
        *(float4*)&bb3[0] = *(const float4*)(SBb + B3IDX(pp, qq, rr));
        float o[4];
        #pragma unroll
        for (int j = 0; j < 4; ++j)
            o[j] = SA[A3IDX(pp * 8 + qq, rr + j)] + bb3[j >> 1][j & 1]
                 + A2pq * bb1[j >> 1][j & 1] + A1p * bb2[j >> 1][j & 1];
        if (h == 0) {
            #pragma unroll
            for (int j = 0; j < 4; ++j) OP[A3IDX(pp * 8 + qq, rr + j)] = o[j];
        } else {
            *(float4*)&OP[B3IDX(pp, qq, rr)] = make_float4(o[0], o[1], o[2], o[3]);
        }
        if (ht < 64) OP[O2 + ht] = SA[O2 + ht] + SBb[O2 + ht] + SA[ht >> 3] * SBb[ht & 7];
        if (ht < 8)  OP[ht] = SA[ht] + SBb[ht];
    }
    __syncthreads();

    // ---- level 2: P = P01 x P23; every element stored by its computer ----
    {
        const int c0 = 2 * w;
        f2 a4[8], b4[8];
        #pragma unroll
        for (int k = 0; k < 4; ++k) {
            float4 v = sT[0][(w * 4 + k) * 64 + l];
            a4[2*k] = mkf2(v.x, v.y); a4[2*k+1] = mkf2(v.z, v.w);
            float4 u = sT[2][(w * 4 + k) * 64 + l];
            b4[2*k] = mkf2(u.x, u.y); b4[2*k+1] = mkf2(u.z, u.w);
        }
        const float A1  = sPA[a];
        const float A2v = sPA[O2 + a * 8 + b];
        const float A3_0 = sPA[A3IDX(a * 8 + b, c0)];
        const float A3_1 = sPA[A3IDX(a * 8 + b, c0 + 1)];
        f2 b1p[4], b2p[8], b3p[8];
        *(float4*)&b1p[0] = *(const float4*)(sPB);
        *(float4*)&b1p[2] = *(const float4*)(sPB + 4);
        #pragma unroll
        for (int i = 0; i < 4; ++i) {
            *(float4*)&b2p[2*i] = *(const float4*)(sPB + O2 + c0 * 8 + 4 * i);
            *(float4*)&b3p[2*i] = *(const float4*)(sPB + B3IDX(b, c0, 0) + 4 * i);
        }
        #pragma unroll
        for (int cc = 0; cc < 2; ++cc) {
            const float A3c = cc ? A3_1 : A3_0;
            #pragma unroll
            for (int j = 0; j < 4; ++j)
                a4[cc*4+j] += b4[cc*4+j] + A3c * b1p[j]
                            + A2v * b2p[cc*4+j] + A1 * b3p[cc*4+j];
        }

        float* dst = ws + (size_t)blockIdx.x * SIG;
        float4* dT = (float4*)(dst + O4);
        #pragma unroll
        for (int k = 0; k < 4; ++k)
            dT[(w * 4 + k) * 64 + l] =
                make_float4(a4[2*k][0], a4[2*k][1], a4[2*k+1][0], a4[2*k+1][1]);
        const int pp = f0 >> 6, qq = (f0 >> 3) & 7, rr = f0 & 7;
        const float A1p  = sPA[pp];
        const float A2pq = sPA[O2 + pp * 8 + qq];
        dst[O3 + f0]     = sPA[A3IDX(pp*8+qq, rr)]     + sPB[B3IDX(pp, qq, rr)]
                         + A2pq * sPB[rr]     + A1p * sPB[O2 + qq * 8 + rr];
        dst[O3 + f0 + 1] = sPA[A3IDX(pp*8+qq, rr + 1)] + sPB[B3IDX(pp, qq, rr + 1)]
                         + A2pq * sPB[rr + 1] + A1p * sPB[O2 + qq * 8 + rr + 1];
        if (tid < 64) dst[O2 + tid] = sPA[O2 + tid] + sPB[O2 + tid] + sPA[tid >> 3] * sPB[tid & 7];
        if (tid < 8)  dst[tid] = sPA[tid] + sPB[tid];
    }
}

// ---------------------------------------------------------------------------
// k2: 256 blocks x 256 thr = (batch n, c-quadrant w4). Tree-combine 4 partials.
// ---------------------------------------------------------------------------
__global__ __launch_bounds__(256) void k2_final(const float* __restrict__ ws,
                                                float* __restrict__ out)
{
    __shared__ __align__(16) float sA0[SB], sB1[SB], sA2[SB], sB3[SB];
    __shared__ __align__(16) float sPA[SB], sPB[SB];

    const int tid = threadIdx.x;
    const int n  = blockIdx.x >> 2;
    const int w4 = blockIdx.x & 3;
    const int a = tid >> 5, b = (tid >> 2) & 7, q = tid & 3;
    const int cc = q >> 1, dh4 = q & 1;
    const int c  = 2 * w4 + cc;
    const int dh = dh4 * 4;
    const int f0 = 2 * tid;
    const float* base = ws + (size_t)n * 4 * SIG;
    const float* s0 = base;
    const float* s1g = base + SIG;
    const float* s2g = base + 2 * SIG;
    const float* s3g = base + 3 * SIG;

    // own L4 quadrant f4 of each sig FIRST (latency overlaps staging)
    const int ti = (w4 * 4 + cc * 2 + dh4) * 64 + (a * 8 + b);
    f2 r0[2], r1[2], r2[2], r3[2];
    {
        float4 u0 = ((const float4*)(s0 + O4))[ti];
        r0[0] = mkf2(u0.x, u0.y); r0[1] = mkf2(u0.z, u0.w);
        float4 u1 = ((const float4*)(s1g + O4))[ti];
        r1[0] = mkf2(u1.x, u1.y); r1[1] = mkf2(u1.z, u1.w);
        float4 u2 = ((const float4*)(s2g + O4))[ti];
        r2[0] = mkf2(u2.x, u2.y); r2[1] = mkf2(u2.z, u2.w);
        float4 u3 = ((const float4*)(s3g + O4))[ti];
        r3[0] = mkf2(u3.x, u3.y); r3[1] = mkf2(u3.z, u3.w);
    }

    // stage: S0,S2 -> A-layout; S1,S3 -> B-layout
    if (tid < O3) { sA0[tid] = s0[tid]; sA2[tid] = s2g[tid]; }
    sA0[A3IDX(f0 >> 3, f0 & 7)]       = s0[O3 + f0];
    sA0[A3IDX(f0 >> 3, (f0 & 7) + 1)] = s0[O3 + f0 + 1];
    sA2[A3IDX(f0 >> 3, f0 & 7)]       = s2g[O3 + f0];
    sA2[A3IDX(f0 >> 3, (f0 & 7) + 1)] = s2g[O3 + f0 + 1];
    if (tid < 146) {
        int d4 = (tid < 18) ? tid : 18 + ((tid - 18) >> 4) * 18 + ((tid - 18) & 15);
        ((float4*)sB1)[d4] = ((const float4*)s1g)[tid];
        ((float4*)sB3)[d4] = ((const float4*)s3g)[tid];
    }
    __syncthreads();

    // ---- level 1: L4 slices per-thread; L123 by half-blocks ----
    f2 p01[2], p23[2];
    {
        const float A1a = sA0[a], A2a = sA0[O2 + a * 8 + b];
        const float A3a = sA0[A3IDX(a * 8 + b, c)];
        f2 b1p[2], b2p[2], b3p[2];
        *(float4*)&b1p[0] = *(const float4*)(sB1 + dh);
        *(float4*)&b2p[0] = *(const float4*)(sB1 + O2 + c * 8 + dh);
        *(float4*)&b3p[0] = *(const float4*)(sB1 + B3IDX(b, c, dh));
        #pragma unroll
        for (int j = 0; j < 2; ++j)
            p01[j] = r0[j] + r1[j] + A3a * b1p[j] + A2a * b2p[j] + A1a * b3p[j];
        const float A1b = sA2[a], A2b = sA2[O2 + a * 8 + b];
        const float A3b = sA2[A3IDX(a * 8 + b, c)];
        f2 c1p[2], c2p[2], c3p[2];
        *(float4*)&c1p[0] = *(const float4*)(sB3 + dh);
        *(float4*)&c2p[0] = *(const float4*)(sB3 + O2 + c * 8 + dh);
        *(float4*)&c3p[0] = *(const float4*)(sB3 + B3IDX(b, c, dh));
        #pragma unroll
        for (int j = 0; j < 2; ++j)
            p23[j] = r2[j] + r3[j] + A3b * c1p[j] + A2b * c2p[j] + A1b * c3p[j];

        const int h  = tid >> 7;
        const int ht = tid & 127;
        const float* SA  = h ? sA2 : sA0;
        const float* SBb = h ? sB3 : sB1;
        float* OP = h ? sPB : sPA;
        const int f3 = ht * 4;
        const int pp = f3 >> 6, qq = (f3 >> 3) & 7, rr = f3 & 7;
        const float A1p  = SA[pp];
        const float A2pq = SA[O2 + pp * 8 + qq];
        f2 bb1[2], bb2[2], bb3[2];
        *(float4*)&bb1[0] = *(const float4*)(SBb + rr);
        *(float4*)&bb2[0] = *(const float4*)(SBb + O2 + qq * 8 + rr);
        *(float4*)&bb3[0] = *(const float4*)(SBb + B3IDX(pp, qq, rr));
        float o[4];
        #pragma unroll
        for (int j = 0; j < 4; ++j)
            o[j] = SA[A3IDX(pp * 8 + qq, rr + j)] + bb3[j >> 1][j & 1]
                 + A2pq * bb1[j >> 1][j & 1] + A1p * bb2[j >> 1][j & 1];
        if (h == 0) {
            #pragma unroll
            for (int j = 0; j < 4; ++j) OP[A3IDX(pp * 8 + qq, rr + j)] = o[j];
        } else {
            *(float4*)&OP[B3IDX(pp, qq, rr)] = make_float4(o[0], o[1], o[2], o[3]);
        }
        if (ht < 64) OP[O2 + ht] = SA[O2 + ht] + SBb[O2 + ht] + SA[ht >> 3] * SBb[ht & 7];
        if (ht < 8)  OP[ht] = SA[ht] + SBb[ht];
    }
    __syncthreads();

    // ---- level 2: final = P01 x P23 ----
    float* dst = out + (size_t)n * SIG;
    {
        const float A1  = sPA[a];
        const float A2v = sPA[O2 + a * 8 + b];
        const float A3c = sPA[A3IDX(a * 8 + b, c)];
        f2 b1p[2], b2p[2], b3p[2];
        *(float4*)&b1p[0] = *(const float4*)(sPB + dh);
        *(float4*)&b2p[0] = *(const float4*)(sPB + O2 + c * 8 + dh);
        *(float4*)&b3p[0] = *(const float4*)(sPB + B3IDX(b, c, dh));
        f2 rf[2];
        #pragma unroll
        for (int j = 0; j < 2; ++j)
            rf[j] = p01[j] + p23[j] + A3c * b1p[j] + A2v * b2p[j] + A1 * b3p[j];
        ((float4*)(dst + O4))[((a * 8 + b) * 8 + c) * 2 + dh4] =
            make_float4(rf[0][0], rf[0][1], rf[1][0], rf[1][1]);
    }
    if (w4 == 0) {   // L123 identical across quadrant blocks; store once
        const int pp = f0 >> 6, qq = (f0 >> 3) & 7, rr = f0 & 7;
        const float A1p  = sPA[pp];
        const float A2pq = sPA[O2 + pp * 8 + qq];
        dst[O3 + f0]     = sPA[A3IDX(pp*8+qq, rr)]     + sPB[B3IDX(pp, qq, rr)]
                         + A2pq * sPB[rr]     + A1p * sPB[O2 + qq * 8 + rr];
        dst[O3 + f0 + 1] = sPA[A3IDX(pp*8+qq, rr + 1)] + sPB[B3IDX(pp, qq, rr + 1)]
                         + A2pq * sPB[rr + 1] + A1p * sPB[O2 + qq * 8 + rr + 1];
        if (tid < 64) dst[O2 + tid] = sPA[O2 + tid] + sPB[O2 + tid] + sPA[tid >> 3] * sPB[tid & 7];
        if (tid < 8)  dst[tid] = sPA[tid] + sPB[tid];
    }
}

extern "C" void kernel_launch(void* const* d_in, const int* in_sizes, int n_in,
                              void* d_out, int out_size, void* d_ws, size_t ws_size,
                              hipStream_t stream) {
    const float* path = (const float*)d_in[0];
    float* out = (float*)d_out;
    float* ws  = (float*)d_ws;   // 256 * 4680 * 4 B = 4.79 MB used

    k1_sig<<<NB * 4, 256, 0, stream>>>(path, ws);
    k2_final<<<NB * 4, 256, 0, stream>>>(ws, out);
}